// Round 1
// 672.812 us; speedup vs baseline: 1.1226x; 1.1226x over previous
//
#include <hip/hip_runtime.h>
#include <stdint.h>

typedef unsigned short u16;
typedef unsigned int u32;
typedef u16 u16x8 __attribute__((ext_vector_type(8)));
typedef u16 u16x4 __attribute__((ext_vector_type(4)));
typedef u16 u16x2 __attribute__((ext_vector_type(2)));
typedef __bf16 bf16x8 __attribute__((ext_vector_type(8)));
typedef float f32x4 __attribute__((ext_vector_type(4)));

__device__ __forceinline__ float bf2f(u16 u) {
    unsigned int x = ((unsigned int)u) << 16;
    float f; __builtin_memcpy(&f, &x, 4); return f;
}
__device__ __forceinline__ u16 f2bf(float f) {
    unsigned int x; __builtin_memcpy(&x, &f, 4);
    x += 0x7fffu + ((x >> 16) & 1u);   // RNE for finite values
    return (u16)(x >> 16);
}
__device__ __forceinline__ float wsum(float v) {
#pragma unroll
    for (int o = 32; o > 0; o >>= 1) v += __shfl_xor(v, o, 64);
    return v;
}

// async global->LDS, 16B per lane (CK-style addrspace casts via uintptr_t)
__device__ __forceinline__ void gload16(const void* g, void* l) {
    const __attribute__((address_space(1))) u32* gp =
        reinterpret_cast<const __attribute__((address_space(1))) u32*>(
            reinterpret_cast<uintptr_t>(g));
    __attribute__((address_space(3))) u32* lp =
        reinterpret_cast<__attribute__((address_space(3))) u32*>(
            reinterpret_cast<uintptr_t>(l));
    __builtin_amdgcn_global_load_lds(gp, lp, 16, 0, 0);
}

// ---------------- fast GEMM (m97 structure): C = A @ Bt^T ----------------
// A  [M,K] bf16 row-major, Bt [N,K] bf16 row-major (pre-transposed weights).
// C [M,N]: fp32 (C_F32=1) or bf16 (C_F32=0).
// 128x128 tile, BK=32, 4 waves, global_load_lds staging, ds_read_b128 frags.
template<int C_F32>
__global__ __launch_bounds__(256) void gemm_bt(
    const u16* __restrict__ A, const u16* __restrict__ Bt,
    void* __restrict__ Cp, int M, int N, int K)
{
    __shared__ __align__(16) u16 sA[128 * 32];   // [m][k], 64B rows
    __shared__ __align__(16) u16 sB[128 * 32];   // [n][k], 64B rows
    const int t = threadIdx.x;
    const int lane = t & 63, wave = t >> 6;
    const int quad = lane >> 4, lr = lane & 15;

    // XCD-aware bijective swizzle (nwg % 8 == 0 for our grids)
    const int nwg = gridDim.x * gridDim.y;
    int id = blockIdx.y * gridDim.x + blockIdx.x;
    int swz = ((nwg & 7) == 0) ? ((id & 7) * (nwg >> 3) + (id >> 3)) : id;
    const int bx = swz % gridDim.x, by = swz / gridDim.x;
    const int m0 = by * 128, n0 = bx * 128;
    const int wm = (wave & 1) * 64, wn = (wave >> 1) * 64;

    // staging: round r in {0,1}: c = t + r*256; row = c>>2; kchunk = (c&3)*8
    const int r0 = t >> 2, kc = (t & 3) * 8;
    const u16* ga = A + (size_t)(m0 + r0) * K + kc;
    const u16* gb = Bt + (size_t)(n0 + r0) * K + kc;
    u16* la = sA + t * 8;
    u16* lb = sB + t * 8;
    const size_t rstride = (size_t)64 * K;       // 64 rows ahead (round 1)

    f32x4 acc[4][4] = {};

    for (int kt = 0; kt < K; kt += 32) {
        __syncthreads();                         // prev iter's LDS reads done
        gload16(ga + kt, la);
        gload16(ga + kt + rstride, la + 2048);
        gload16(gb + kt, lb);
        gload16(gb + kt + rstride, lb + 2048);
        __syncthreads();                         // compiler drains vmcnt before barrier

        bf16x8 af[4], bfr[4];
#pragma unroll
        for (int i = 0; i < 4; ++i)
            af[i] = *(const bf16x8*)(sA + (wm + i * 16 + lr) * 32 + quad * 8);
#pragma unroll
        for (int j = 0; j < 4; ++j)
            bfr[j] = *(const bf16x8*)(sB + (wn + j * 16 + lr) * 32 + quad * 8);
#pragma unroll
        for (int i = 0; i < 4; ++i)
#pragma unroll
            for (int j = 0; j < 4; ++j)
                acc[i][j] = __builtin_amdgcn_mfma_f32_16x16x32_bf16(af[i], bfr[j], acc[i][j], 0, 0, 0);
    }
    // epilogue: C/D layout col=lane&15, row=quad*4+r
#pragma unroll
    for (int i = 0; i < 4; ++i) {
        int mrow = m0 + wm + i * 16 + quad * 4;
#pragma unroll
        for (int j = 0; j < 4; ++j) {
            int ncol = n0 + wn + j * 16 + lr;
#pragma unroll
            for (int r = 0; r < 4; ++r) {
                if (C_F32) ((float*)Cp)[(size_t)(mrow + r) * N + ncol] = acc[i][j][r];
                else       ((u16*)Cp)[(size_t)(mrow + r) * N + ncol] = f2bf(acc[i][j][r]);
            }
        }
    }
}

// ---------------- prep: fp32 -> bf16 streaming convert ----------------
__global__ __launch_bounds__(256) void f32_to_bf16(
    const float* __restrict__ in, u16* __restrict__ out, int n8)
{
    int i = blockIdx.x * 256 + threadIdx.x;
    const int stride = gridDim.x * 256;
    for (; i < n8; i += stride) {
        f32x4 a = *(const f32x4*)(in + (size_t)i * 8);
        f32x4 b = *(const f32x4*)(in + (size_t)i * 8 + 4);
        u16x8 o;
#pragma unroll
        for (int p = 0; p < 4; ++p) { o[p] = f2bf(a[p]); o[p + 4] = f2bf(b[p]); }
        *(u16x8*)(out + (size_t)i * 8) = o;
    }
}

// ---------------- prep: W[K][N] fp32 -> Bt[N][K] bf16 (64x64 LDS tiles) ----------------
__global__ __launch_bounds__(256) void w_transpose(
    const float* __restrict__ W, u16* __restrict__ Bt, int K, int N)
{
    __shared__ u16 tile[64][72];
    const int t = threadIdx.x;
    const int c4 = (t & 15) * 4;
    const int r0 = t >> 4;
    const int kb = blockIdx.y * 64, nb = blockIdx.x * 64;
#pragma unroll
    for (int p = 0; p < 4; ++p) {
        int k = p * 16 + r0;
        f32x4 v = *(const f32x4*)(W + (size_t)(kb + k) * N + nb + c4);
        u16x4 o;
#pragma unroll
        for (int j = 0; j < 4; ++j) o[j] = f2bf(v[j]);
        *(u16x4*)&tile[k][c4] = o;
    }
    __syncthreads();
#pragma unroll
    for (int p = 0; p < 4; ++p) {
        int n = p * 16 + r0;
        u16x4 o;
#pragma unroll
        for (int j = 0; j < 4; ++j) o[j] = tile[c4 + j][n];
        *(u16x4*)(Bt + (size_t)(nb + n) * K + kb + c4) = o;
    }
}

// ---------------- fallback GEMM (old reg-staged path, tight-ws only) ----------------
#define BM 128
#define BN 128
#define BKK 32
#define SBS (BN + 2)
template<int A_F32, int C_F32>
__global__ __launch_bounds__(256) void gemm_k(
    const void* __restrict__ Ap, const float* __restrict__ B,
    void* __restrict__ Cp, int M, int N, int K)
{
    __shared__ __align__(16) u16 sA[BM * BKK];
    __shared__ __align__(16) u16 sB[BKK * SBS];
    const int t = threadIdx.x;
    const int lane = t & 63, wave = t >> 6;
    const int m0 = blockIdx.y * BM, n0 = blockIdx.x * BN;
    const int wm = (wave & 1) * 64, wn = (wave >> 1) * 64;
    const int quad = lane >> 4, lr = lane & 15;

    f32x4 acc[4][4] = {};

    for (int kt = 0; kt < K; kt += BKK) {
        u16x8 va[2], vb[2];
#pragma unroll
        for (int r = 0; r < 2; ++r) {
            int c = t + r * 256;
            int arow = c >> 2, aks = (c & 3) * 8;
            if (A_F32) {
                const float* ga = (const float*)Ap + (size_t)(m0 + arow) * K + kt + aks;
                f32x4 f0 = *(const f32x4*)ga;
                f32x4 f1 = *(const f32x4*)(ga + 4);
#pragma unroll
                for (int p = 0; p < 4; ++p) { va[r][p] = f2bf(f0[p]); va[r][p + 4] = f2bf(f1[p]); }
            } else {
                va[r] = *(const u16x8*)((const u16*)Ap + (size_t)(m0 + arow) * K + kt + aks);
            }
            int bk = c >> 4, bn = (c & 15) * 8;
            const float* gb = B + (size_t)(kt + bk) * N + n0 + bn;
            f32x4 g0 = *(const f32x4*)gb;
            f32x4 g1 = *(const f32x4*)(gb + 4);
#pragma unroll
            for (int p = 0; p < 4; ++p) { vb[r][p] = f2bf(g0[p]); vb[r][p + 4] = f2bf(g1[p]); }
        }
        __syncthreads();
#pragma unroll
        for (int r = 0; r < 2; ++r) {
            int c = t + r * 256;
            *(u16x8*)((char*)sA + (size_t)c * 16) = va[r];
            int bk = c >> 4, bn = (c & 15) * 8;
            u16* dst = sB + bk * SBS + bn;
#pragma unroll
            for (int p = 0; p < 4; ++p) {
                u16x2 w; w[0] = vb[r][2 * p]; w[1] = vb[r][2 * p + 1];
                *(u16x2*)(dst + 2 * p) = w;
            }
        }
        __syncthreads();

        bf16x8 af[4], bfr[4];
#pragma unroll
        for (int i = 0; i < 4; ++i)
            af[i] = *(const bf16x8*)((const char*)sA + (wm + i * 16 + lr) * 64 + quad * 16);
#pragma unroll
        for (int i = 0; i < 4; ++i) {
            u16 tmp[8];
#pragma unroll
            for (int j = 0; j < 8; ++j)
                tmp[j] = sB[(quad * 8 + j) * SBS + (wn + i * 16 + lr)];
            __builtin_memcpy(&bfr[i], tmp, 16);
        }
#pragma unroll
        for (int i = 0; i < 4; ++i)
#pragma unroll
            for (int j = 0; j < 4; ++j)
                acc[i][j] = __builtin_amdgcn_mfma_f32_16x16x32_bf16(af[i], bfr[j], acc[i][j], 0, 0, 0);
    }
#pragma unroll
    for (int i = 0; i < 4; ++i) {
        int mrow = m0 + wm + i * 16 + quad * 4;
#pragma unroll
        for (int j = 0; j < 4; ++j) {
            int ncol = n0 + wn + j * 16 + lr;
#pragma unroll
            for (int r = 0; r < 4; ++r) {
                if (C_F32) ((float*)Cp)[(size_t)(mrow + r) * N + ncol] = acc[i][j][r];
                else       ((u16*)Cp)[(size_t)(mrow + r) * N + ncol] = f2bf(acc[i][j][r]);
            }
        }
    }
}

// ---------------- LN1 + hierarchical fusion (wave per row; bf16 y in, bf16 out) ----------------
__global__ __launch_bounds__(256) void ln1_fusion(
    const u16* Y, const float* __restrict__ ltb,
    const float* __restrict__ g1, const float* __restrict__ b1,
    const float* __restrict__ masks, const float* __restrict__ emb,
    u16* fused, int ROWS)
{
    const int lane = threadIdx.x & 63;
    const int wid = blockIdx.x * (blockDim.x >> 6) + (threadIdx.x >> 6);
    const int nw = gridDim.x * (blockDim.x >> 6);
    const int h0 = lane * 16;

    float ltbv[16], gv[16], bv[16], ev[4][16];
#pragma unroll
    for (int i = 0; i < 16; ++i) {
        ltbv[i] = ltb[h0 + i];
        gv[i] = g1[h0 + i];
        bv[i] = b1[h0 + i];
    }
#pragma unroll
    for (int n = 0; n < 4; ++n)
#pragma unroll
        for (int i = 0; i < 16; ++i) ev[n][i] = emb[n * 1024 + h0 + i];

    for (int r = wid; r < ROWS; r += nw) {
        const u16* yrow = Y + (size_t)r * 1024 + h0;
        u16x8 v0 = *(const u16x8*)(yrow);
        u16x8 v1 = *(const u16x8*)(yrow + 8);
        float y[16], s = 0.f, sq = 0.f;
#pragma unroll
        for (int i = 0; i < 8; ++i) { y[i] = bf2f(v0[i]) + ltbv[i]; y[i + 8] = bf2f(v1[i]) + ltbv[i + 8]; }
#pragma unroll
        for (int i = 0; i < 16; ++i) { s += y[i]; sq += y[i] * y[i]; }
        s = wsum(s); sq = wsum(sq);
        float mu = s * (1.f / 1024.f);
        float var = fmaxf(sq * (1.f / 1024.f) - mu * mu, 0.f);
        float rinv = rsqrtf(var + 1e-5f);
        float tv[16];
#pragma unroll
        for (int i = 0; i < 16; ++i) tv[i] = (y[i] - mu) * rinv * gv[i] + bv[i];

        float p0 = 0.f, p1 = 0.f, p2 = 0.f, p3 = 0.f;
#pragma unroll
        for (int i = 0; i < 16; ++i) {
            p0 += tv[i] * ev[0][i]; p1 += tv[i] * ev[1][i];
            p2 += tv[i] * ev[2][i]; p3 += tv[i] * ev[3][i];
        }
        p0 = wsum(p0); p1 = wsum(p1); p2 = wsum(p2); p3 = wsum(p3);
        p0 = fminf(p0, 30.f); p1 = fminf(p1, 30.f); p2 = fminf(p2, 30.f); p3 = fminf(p3, 30.f);

        f32x4 mk = *(const f32x4*)(masks + (size_t)r * 4);
        float w0 = mk[0] > 0.5f ? expf(p0) : 0.f;
        float w1 = mk[1] > 0.5f ? expf(p1) : 0.f;
        float w2 = mk[2] > 0.5f ? expf(p2) : 0.f;
        float w3 = mk[3] > 0.5f ? expf(p3) : 0.f;
        float tot = w0 + w1 + w2 + w3;
        float inv = tot > 1e-8f ? 1.f / tot : 1.f;

        float fu[16], d = 0.f;
#pragma unroll
        for (int i = 0; i < 16; ++i) {
            fu[i] = (w0 * ev[0][i] + w1 * ev[1][i] + w2 * ev[2][i] + w3 * ev[3][i]) * inv;
            d += fu[i] * tv[i];
        }
        d = wsum(d);
        float gate = 1.f / (1.f + expf(fminf(-d * (1.f / 1024.f), 30.f)));

        u16x8 o0, o1;
#pragma unroll
        for (int i = 0; i < 8; ++i) {
            o0[i] = f2bf(gate * fu[i] + (1.f - gate) * tv[i]);
            o1[i] = f2bf(gate * fu[i + 8] + (1.f - gate) * tv[i + 8]);
        }
        u16* orow = fused + (size_t)r * 1024 + h0;
        *(u16x8*)(orow) = o0;
        *(u16x8*)(orow + 8) = o1;
    }
}

// ---------------- multi-scale windowed means (bf16 -> bf16) ----------------
__global__ __launch_bounds__(256) void multiscale(
    const u16* __restrict__ fused, u16* __restrict__ agg, int L)
{
    const int bl = blockIdx.x;        // b*L + l
    const int b = bl / L, l = bl - b * L;
    const int h0 = threadIdx.x * 4;

    const float sw[4] = { 1.f, 1.f / (1.f + logf(3.f)), 1.f / (1.f + logf(7.f)), 1.f / (1.f + logf(15.f)) };
    const int half[4] = { 0, 1, 3, 7 };
    float coef[4];
#pragma unroll
    for (int s = 0; s < 4; ++s) {
        int st = l - half[s]; if (st < 0) st = 0;
        int en = l + half[s] + 1; if (en > L) en = L;
        coef[s] = sw[s] / (float)(en - st);
    }
    float a0 = 0.f, a1 = 0.f, a2 = 0.f, a3 = 0.f;
#pragma unroll
    for (int d = -7; d <= 7; ++d) {
        int j = l + d;
        if ((unsigned)j >= (unsigned)L) continue;
        int ad = d < 0 ? -d : d;
        float c = coef[3];
        if (ad <= 3) c += coef[2];
        if (ad <= 1) c += coef[1];
        if (ad == 0) c += coef[0];
        u16x4 v = *(const u16x4*)(fused + ((size_t)(b * L + j)) * 1024 + h0);
        a0 += c * bf2f(v[0]); a1 += c * bf2f(v[1]);
        a2 += c * bf2f(v[2]); a3 += c * bf2f(v[3]);
    }
    u16x4 o; o[0] = f2bf(a0); o[1] = f2bf(a1); o[2] = f2bf(a2); o[3] = f2bf(a3);
    *(u16x4*)(agg + (size_t)bl * 1024 + h0) = o;
}

// ---------------- LN2 + residual, fp32 in-place on d_out ----------------
__global__ __launch_bounds__(256) void ln2_res(
    float* Y, const float* __restrict__ ftb,
    const float* __restrict__ g2, const float* __restrict__ b2,
    const float* __restrict__ x, int ROWS)
{
    const int lane = threadIdx.x & 63;
    const int wid = blockIdx.x * (blockDim.x >> 6) + (threadIdx.x >> 6);
    const int nw = gridDim.x * (blockDim.x >> 6);
    const int h0 = lane * 16;

    float ftbv[16], gv[16], bv[16];
#pragma unroll
    for (int i = 0; i < 16; ++i) {
        ftbv[i] = ftb[h0 + i];
        gv[i] = g2[h0 + i];
        bv[i] = b2[h0 + i];
    }
    for (int r = wid; r < ROWS; r += nw) {
        float* yrow = Y + (size_t)r * 1024 + h0;
        float y[16], s = 0.f, sq = 0.f;
#pragma unroll
        for (int q = 0; q < 4; ++q) {
            f32x4 v = *(const f32x4*)(yrow + 4 * q);
#pragma unroll
            for (int p = 0; p < 4; ++p) y[4 * q + p] = v[p] + ftbv[4 * q + p];
        }
#pragma unroll
        for (int i = 0; i < 16; ++i) { s += y[i]; sq += y[i] * y[i]; }
        s = wsum(s); sq = wsum(sq);
        float mu = s * (1.f / 1024.f);
        float var = fmaxf(sq * (1.f / 1024.f) - mu * mu, 0.f);
        float rinv = rsqrtf(var + 1e-5f);

        const float* xrow = x + (size_t)r * 1024 + h0;
#pragma unroll
        for (int q = 0; q < 4; ++q) {
            f32x4 xv = *(const f32x4*)(xrow + 4 * q);
            f32x4 o;
#pragma unroll
            for (int p = 0; p < 4; ++p)
                o[p] = (y[4 * q + p] - mu) * rinv * gv[4 * q + p] + bv[4 * q + p] + xv[p];
            *(f32x4*)(yrow + 4 * q) = o;
        }
    }
}

extern "C" void kernel_launch(void* const* d_in, const int* in_sizes, int n_in,
                              void* d_out, int out_size, void* d_ws, size_t ws_size,
                              hipStream_t stream) {
    const float* x     = (const float*)d_in[0];   // [B,L,H] fp32
    const float* masks = (const float*)d_in[1];   // [B,L,4] fp32
    const float* emb   = (const float*)d_in[2];   // [4,H]   fp32
    const float* ltw   = (const float*)d_in[3];   // [H,H]   fp32
    const float* ltb   = (const float*)d_in[4];
    const float* g1    = (const float*)d_in[5];
    const float* b1    = (const float*)d_in[6];
    const float* ftw   = (const float*)d_in[7];   // [H,H]   fp32
    const float* ftb   = (const float*)d_in[8];
    const float* g2    = (const float*)d_in[9];
    const float* b2    = (const float*)d_in[10];
    float* out = (float*)d_out;                   // [B,L,H] fp32 (128 MB)

    const int H = 1024, L = 4096;
    const int M = in_sizes[0] / H;                // B*L = 32768
    const size_t MB = 1024 * 1024;

    // memory plan:
    //  d_out lower 64 MB : plane0 (bf16 y1 / fused) — dead before fp32 C-write of GEMM2
    //  d_out upper 64 MB : x_bf16 (A for GEMM1)     — dead before GEMM2's C-write
    //  ws[0:64MB]        : aggP bf16
    //  ws[64:66MB]       : Bt1 (ltw^T bf16)   (tight-ws: Bt1 aliases ws[0:2MB], dead before aggP written)
    //  ws[66:68MB]       : Bt2 (ftw^T bf16)   (tight-ws: unavailable -> old reg-staged GEMM2)
    u16* plane0 = (u16*)d_out;
    u16* xbf    = (u16*)((char*)d_out + 64 * MB);
    u16* aggP   = (u16*)d_ws;
    const bool roomy = ws_size >= 68 * MB;
    u16* Bt1 = roomy ? (u16*)((char*)d_ws + 64 * MB) : (u16*)d_ws;
    u16* Bt2 = roomy ? (u16*)((char*)d_ws + 66 * MB) : nullptr;

    // prep: one-time bf16 conversions (identical RNE rounding to the old in-loop f2bf)
    f32_to_bf16<<<2048, 256, 0, stream>>>(x, xbf, M * H / 8);
    w_transpose<<<dim3(16, 16), 256, 0, stream>>>(ltw, Bt1, H, H);
    if (roomy) w_transpose<<<dim3(16, 16), 256, 0, stream>>>(ftw, Bt2, H, H);

    gemm_bt<0><<<dim3(H / 128, M / 128), 256, 0, stream>>>(xbf, Bt1, plane0, M, H, H);  // y1 bf16
    ln1_fusion<<<1024, 256, 0, stream>>>(plane0, ltb, g1, b1, masks, emb, plane0, M);   // fused in-place
    multiscale<<<M, 256, 0, stream>>>(plane0, aggP, L);                                 // agg bf16 -> ws
    if (roomy)
        gemm_bt<1><<<dim3(H / 128, M / 128), 256, 0, stream>>>(aggP, Bt2, out, M, H, H);
    else
        gemm_k<0, 1><<<dim3(H / BN, M / BM), 256, 0, stream>>>(aggP, ftw, out, M, H, H);
    ln2_res<<<1024, 256, 0, stream>>>(out, ftb, g2, b2, x, M);                          // LN2 + residual
}

// Round 3
// 586.272 us; speedup vs baseline: 1.2883x; 1.1476x over previous
//
#include <hip/hip_runtime.h>
#include <stdint.h>

typedef unsigned short u16;
typedef unsigned int u32;
typedef u16 u16x8 __attribute__((ext_vector_type(8)));
typedef u16 u16x4 __attribute__((ext_vector_type(4)));
typedef u16 u16x2 __attribute__((ext_vector_type(2)));
typedef __bf16 bf16x8 __attribute__((ext_vector_type(8)));
typedef float f32x4 __attribute__((ext_vector_type(4)));

__device__ __forceinline__ float bf2f(u16 u) {
    unsigned int x = ((unsigned int)u) << 16;
    float f; __builtin_memcpy(&f, &x, 4); return f;
}
__device__ __forceinline__ u16 f2bf(float f) {
    unsigned int x; __builtin_memcpy(&x, &f, 4);
    x += 0x7fffu + ((x >> 16) & 1u);   // RNE for finite values
    return (u16)(x >> 16);
}
__device__ __forceinline__ float wsum(float v) {
#pragma unroll
    for (int o = 32; o > 0; o >>= 1) v += __shfl_xor(v, o, 64);
    return v;
}

// async global->LDS, 16B per lane (proven in gemm_bt, Round 1)
__device__ __forceinline__ void gload16(const void* g, void* l) {
    const __attribute__((address_space(1))) u32* gp =
        reinterpret_cast<const __attribute__((address_space(1))) u32*>(
            reinterpret_cast<uintptr_t>(g));
    __attribute__((address_space(3))) u32* lp =
        reinterpret_cast<__attribute__((address_space(3))) u32*>(
            reinterpret_cast<uintptr_t>(l));
    __builtin_amdgcn_global_load_lds(gp, lp, 16, 0, 0);
}

// ---------------- fast GEMM (m97 structure): C = A @ Bt^T ----------------
// A  [M,K] bf16 row-major, Bt [N,K] bf16 row-major (pre-transposed weights).
// C [M,N]: fp32 (C_F32=1) or bf16 (C_F32=0).
template<int C_F32>
__global__ __launch_bounds__(256) void gemm_bt(
    const u16* __restrict__ A, const u16* __restrict__ Bt,
    void* __restrict__ Cp, int M, int N, int K)
{
    __shared__ __align__(16) u16 sA[128 * 32];   // [m][k], 64B rows
    __shared__ __align__(16) u16 sB[128 * 32];   // [n][k], 64B rows
    const int t = threadIdx.x;
    const int lane = t & 63, wave = t >> 6;
    const int quad = lane >> 4, lr = lane & 15;

    // XCD-aware bijective swizzle (nwg % 8 == 0 for our grids)
    const int nwg = gridDim.x * gridDim.y;
    int id = blockIdx.y * gridDim.x + blockIdx.x;
    int swz = ((nwg & 7) == 0) ? ((id & 7) * (nwg >> 3) + (id >> 3)) : id;
    const int bx = swz % gridDim.x, by = swz / gridDim.x;
    const int m0 = by * 128, n0 = bx * 128;
    const int wm = (wave & 1) * 64, wn = (wave >> 1) * 64;

    const int r0 = t >> 2, kc = (t & 3) * 8;
    const u16* ga = A + (size_t)(m0 + r0) * K + kc;
    const u16* gb = Bt + (size_t)(n0 + r0) * K + kc;
    u16* la = sA + t * 8;
    u16* lb = sB + t * 8;
    const size_t rstride = (size_t)64 * K;

    f32x4 acc[4][4] = {};

    for (int kt = 0; kt < K; kt += 32) {
        __syncthreads();
        gload16(ga + kt, la);
        gload16(ga + kt + rstride, la + 2048);
        gload16(gb + kt, lb);
        gload16(gb + kt + rstride, lb + 2048);
        __syncthreads();

        bf16x8 af[4], bfr[4];
#pragma unroll
        for (int i = 0; i < 4; ++i)
            af[i] = *(const bf16x8*)(sA + (wm + i * 16 + lr) * 32 + quad * 8);
#pragma unroll
        for (int j = 0; j < 4; ++j)
            bfr[j] = *(const bf16x8*)(sB + (wn + j * 16 + lr) * 32 + quad * 8);
#pragma unroll
        for (int i = 0; i < 4; ++i)
#pragma unroll
            for (int j = 0; j < 4; ++j)
                acc[i][j] = __builtin_amdgcn_mfma_f32_16x16x32_bf16(af[i], bfr[j], acc[i][j], 0, 0, 0);
    }
#pragma unroll
    for (int i = 0; i < 4; ++i) {
        int mrow = m0 + wm + i * 16 + quad * 4;
#pragma unroll
        for (int j = 0; j < 4; ++j) {
            int ncol = n0 + wn + j * 16 + lr;
#pragma unroll
            for (int r = 0; r < 4; ++r) {
                if (C_F32) ((float*)Cp)[(size_t)(mrow + r) * N + ncol] = acc[i][j][r];
                else       ((u16*)Cp)[(size_t)(mrow + r) * N + ncol] = f2bf(acc[i][j][r]);
            }
        }
    }
}

// ---------------- prep: fp32 -> bf16 streaming convert ----------------
__global__ __launch_bounds__(256) void f32_to_bf16(
    const float* __restrict__ in, u16* __restrict__ out, int n8)
{
    int i = blockIdx.x * 256 + threadIdx.x;
    const int stride = gridDim.x * 256;
    for (; i < n8; i += stride) {
        f32x4 a = *(const f32x4*)(in + (size_t)i * 8);
        f32x4 b = *(const f32x4*)(in + (size_t)i * 8 + 4);
        u16x8 o;
#pragma unroll
        for (int p = 0; p < 4; ++p) { o[p] = f2bf(a[p]); o[p + 4] = f2bf(b[p]); }
        *(u16x8*)(out + (size_t)i * 8) = o;
    }
}

// ---------------- prep: W[K][N] fp32 -> Bt[N][K] bf16 ----------------
__global__ __launch_bounds__(256) void w_transpose(
    const float* __restrict__ W, u16* __restrict__ Bt, int K, int N)
{
    __shared__ u16 tile[64][72];
    const int t = threadIdx.x;
    const int c4 = (t & 15) * 4;
    const int r0 = t >> 4;
    const int kb = blockIdx.y * 64, nb = blockIdx.x * 64;
#pragma unroll
    for (int p = 0; p < 4; ++p) {
        int k = p * 16 + r0;
        f32x4 v = *(const f32x4*)(W + (size_t)(kb + k) * N + nb + c4);
        u16x4 o;
#pragma unroll
        for (int j = 0; j < 4; ++j) o[j] = f2bf(v[j]);
        *(u16x4*)&tile[k][c4] = o;
    }
    __syncthreads();
#pragma unroll
    for (int p = 0; p < 4; ++p) {
        int n = p * 16 + r0;
        u16x4 o;
#pragma unroll
        for (int j = 0; j < 4; ++j) o[j] = tile[c4 + j][n];
        *(u16x4*)(Bt + (size_t)(nb + n) * K + kb + c4) = o;
    }
}

// ---------------- LN1 + hierarchical fusion ----------------
__global__ __launch_bounds__(256) void ln1_fusion(
    const u16* Y, const float* __restrict__ ltb,
    const float* __restrict__ g1, const float* __restrict__ b1,
    const float* __restrict__ masks, const float* __restrict__ emb,
    u16* fused, int ROWS)
{
    const int lane = threadIdx.x & 63;
    const int wid = blockIdx.x * (blockDim.x >> 6) + (threadIdx.x >> 6);
    const int nw = gridDim.x * (blockDim.x >> 6);
    const int h0 = lane * 16;

    float ltbv[16], gv[16], bv[16], ev[4][16];
#pragma unroll
    for (int i = 0; i < 16; ++i) {
        ltbv[i] = ltb[h0 + i];
        gv[i] = g1[h0 + i];
        bv[i] = b1[h0 + i];
    }
#pragma unroll
    for (int n = 0; n < 4; ++n)
#pragma unroll
        for (int i = 0; i < 16; ++i) ev[n][i] = emb[n * 1024 + h0 + i];

    for (int r = wid; r < ROWS; r += nw) {
        const u16* yrow = Y + (size_t)r * 1024 + h0;
        u16x8 v0 = *(const u16x8*)(yrow);
        u16x8 v1 = *(const u16x8*)(yrow + 8);
        float y[16], s = 0.f, sq = 0.f;
#pragma unroll
        for (int i = 0; i < 8; ++i) { y[i] = bf2f(v0[i]) + ltbv[i]; y[i + 8] = bf2f(v1[i]) + ltbv[i + 8]; }
#pragma unroll
        for (int i = 0; i < 16; ++i) { s += y[i]; sq += y[i] * y[i]; }
        s = wsum(s); sq = wsum(sq);
        float mu = s * (1.f / 1024.f);
        float var = fmaxf(sq * (1.f / 1024.f) - mu * mu, 0.f);
        float rinv = rsqrtf(var + 1e-5f);
        float tv[16];
#pragma unroll
        for (int i = 0; i < 16; ++i) tv[i] = (y[i] - mu) * rinv * gv[i] + bv[i];

        float p0 = 0.f, p1 = 0.f, p2 = 0.f, p3 = 0.f;
#pragma unroll
        for (int i = 0; i < 16; ++i) {
            p0 += tv[i] * ev[0][i]; p1 += tv[i] * ev[1][i];
            p2 += tv[i] * ev[2][i]; p3 += tv[i] * ev[3][i];
        }
        p0 = wsum(p0); p1 = wsum(p1); p2 = wsum(p2); p3 = wsum(p3);
        p0 = fminf(p0, 30.f); p1 = fminf(p1, 30.f); p2 = fminf(p2, 30.f); p3 = fminf(p3, 30.f);

        f32x4 mk = *(const f32x4*)(masks + (size_t)r * 4);
        float w0 = mk[0] > 0.5f ? expf(p0) : 0.f;
        float w1 = mk[1] > 0.5f ? expf(p1) : 0.f;
        float w2 = mk[2] > 0.5f ? expf(p2) : 0.f;
        float w3 = mk[3] > 0.5f ? expf(p3) : 0.f;
        float tot = w0 + w1 + w2 + w3;
        float inv = tot > 1e-8f ? 1.f / tot : 1.f;

        float fu[16], d = 0.f;
#pragma unroll
        for (int i = 0; i < 16; ++i) {
            fu[i] = (w0 * ev[0][i] + w1 * ev[1][i] + w2 * ev[2][i] + w3 * ev[3][i]) * inv;
            d += fu[i] * tv[i];
        }
        d = wsum(d);
        float gate = 1.f / (1.f + expf(fminf(-d * (1.f / 1024.f), 30.f)));

        u16x8 o0, o1;
#pragma unroll
        for (int i = 0; i < 8; ++i) {
            o0[i] = f2bf(gate * fu[i] + (1.f - gate) * tv[i]);
            o1[i] = f2bf(gate * fu[i + 8] + (1.f - gate) * tv[i + 8]);
        }
        u16* orow = fused + (size_t)r * 1024 + h0;
        *(u16x8*)(orow) = o0;
        *(u16x8*)(orow + 8) = o1;
    }
}

// ---------------- multi-scale: LDS-staged sliding windows ----------------
// Block: one b, 64-long l-segment, 512-wide h-half. Stage (64+14) rows into
// LDS once via reg-staged vector copies (zero-padded halo == reference's
// window clipping). Each thread owns 8 h-cols x 16 l, keeps nested window
// sums S3/S7/S15 in registers and slides them (+new -old) along l.
// Every fused elem read from HBM once (+22% halo).
#define MS_SEG 64
#define MS_HH 512
#define MS_ROWS (MS_SEG + 14)   // 78 rows, 78*512*2 = 79872 B LDS
__global__ __launch_bounds__(256) void multiscale_slide(
    const u16* __restrict__ fused, u16* __restrict__ agg, int L)
{
    __shared__ __align__(16) u16 sT[MS_ROWS * MS_HH];
    const int t = threadIdx.x;
    const int lane = t & 63, wave = t >> 6;
    const int hhalf = blockIdx.x & 1;
    const int bseg = blockIdx.x >> 1;
    const int nseg = L / MS_SEG;
    const int b = bseg / nseg, seg = bseg - b * nseg;
    const int l0 = seg * MS_SEG;
    const size_t base = (size_t)b * L * 1024 + (size_t)hhalf * MS_HH;  // u16 offset at l=0

    // ---- stage rows l0-7 .. l0+70 (zero-pad out-of-range), reg-staged ----
    for (int r = wave; r < MS_ROWS; r += 4) {
        int gl = l0 + r - 7;
        u16x8 v = {};
        if ((unsigned)gl < (unsigned)L)
            v = *(const u16x8*)(fused + base + (size_t)gl * 1024 + lane * 8);
        *(u16x8*)(sT + r * MS_HH + lane * 8) = v;
    }
    __syncthreads();

    const int h0 = lane * 8;             // 64 lanes cover 512 u16
    const int lq = wave;                 // wave id = l-quarter (0..3)
    const u16* rowp = sT + (lq * 16) * MS_HH + h0;  // relative row 0

#define LOADR(dst, rr) { u16x8 _v = *(const u16x8*)(rowp + (rr) * MS_HH); \
    _Pragma("unroll") for (int e = 0; e < 8; ++e) dst[e] = bf2f(_v[e]); }

    float fc[8], a3[8], a7[8], a15[8];
    {
        float u[8], v[8];
        LOADR(fc, 7);
        LOADR(u, 6); LOADR(v, 8);
#pragma unroll
        for (int e = 0; e < 8; ++e) a3[e] = fc[e] + u[e] + v[e];
        LOADR(u, 5); LOADR(v, 9);
#pragma unroll
        for (int e = 0; e < 8; ++e) a7[e] = a3[e] + u[e] + v[e];
        LOADR(u, 4); LOADR(v, 10);
#pragma unroll
        for (int e = 0; e < 8; ++e) a7[e] += u[e] + v[e];
        LOADR(u, 3); LOADR(v, 11);
#pragma unroll
        for (int e = 0; e < 8; ++e) a15[e] = a7[e] + u[e] + v[e];
        LOADR(u, 2); LOADR(v, 12);
#pragma unroll
        for (int e = 0; e < 8; ++e) a15[e] += u[e] + v[e];
        LOADR(u, 1); LOADR(v, 13);
#pragma unroll
        for (int e = 0; e < 8; ++e) a15[e] += u[e] + v[e];
        LOADR(u, 0); LOADR(v, 14);
#pragma unroll
        for (int e = 0; e < 8; ++e) a15[e] += u[e] + v[e];
    }

    const float SW1 = 1.f / (1.f + logf(3.f));
    const float SW2 = 1.f / (1.f + logf(7.f));
    const float SW3 = 1.f / (1.f + logf(15.f));
    const float C1 = SW1 / 3.f, C2 = SW2 / 7.f, C3 = SW3 / 15.f;

    u16* outp = agg + base + (size_t)(l0 + lq * 16) * 1024 + h0;
#pragma unroll
    for (int i = 0; i < 16; ++i) {
        const int l = l0 + lq * 16 + i;
        float c1 = C1, c2 = C2, c3 = C3;
        if (l < 7 || l + 7 >= L) {   // sequence-edge counts (scale-1 cnt always 1)
            int s1 = l - 1 < 0 ? 0 : l - 1, e1 = l + 2 > L ? L : l + 2;
            int s2 = l - 3 < 0 ? 0 : l - 3, e2 = l + 4 > L ? L : l + 4;
            int s3 = l - 7 < 0 ? 0 : l - 7, e3 = l + 8 > L ? L : l + 8;
            c1 = SW1 / (float)(e1 - s1);
            c2 = SW2 / (float)(e2 - s2);
            c3 = SW3 / (float)(e3 - s3);
        }
        u16x8 o;
#pragma unroll
        for (int e = 0; e < 8; ++e)
            o[e] = f2bf(fc[e] + c1 * a3[e] + c2 * a7[e] + c3 * a15[e]);
        *(u16x8*)(outp + (size_t)i * 1024) = o;

        if (i < 15) {   // slide center from l to l+1
            float p1[8], p2[8], m1[8], p4[8], m3[8], p8[8], m7[8];
            LOADR(p1, 7 + i + 1); LOADR(p2, 7 + i + 2); LOADR(m1, 7 + i - 1);
            LOADR(p4, 7 + i + 4); LOADR(m3, 7 + i - 3);
            LOADR(p8, 7 + i + 8); LOADR(m7, 7 + i - 7);
#pragma unroll
            for (int e = 0; e < 8; ++e) {
                a3[e]  += p2[e] - m1[e];
                a7[e]  += p4[e] - m3[e];
                a15[e] += p8[e] - m7[e];
                fc[e]   = p1[e];
            }
        }
    }
#undef LOADR
}

// ---------------- fallback GEMM (old reg-staged path, tight-ws only) ----------------
#define BM 128
#define BN 128
#define BKK 32
#define SBS (BN + 2)
__global__ __launch_bounds__(256) void gemm_k_bf_f32(
    const u16* __restrict__ Ap, const float* __restrict__ B,
    float* __restrict__ Cp, int M, int N, int K)
{
    __shared__ __align__(16) u16 sA[BM * BKK];
    __shared__ __align__(16) u16 sB[BKK * SBS];
    const int t = threadIdx.x;
    const int lane = t & 63, wave = t >> 6;
    const int m0 = blockIdx.y * BM, n0 = blockIdx.x * BN;
    const int wm = (wave & 1) * 64, wn = (wave >> 1) * 64;
    const int quad = lane >> 4, lr = lane & 15;

    f32x4 acc[4][4] = {};

    for (int kt = 0; kt < K; kt += BKK) {
        u16x8 va[2], vb[2];
#pragma unroll
        for (int r = 0; r < 2; ++r) {
            int c = t + r * 256;
            int arow = c >> 2, aks = (c & 3) * 8;
            va[r] = *(const u16x8*)(Ap + (size_t)(m0 + arow) * K + kt + aks);
            int bk = c >> 4, bn = (c & 15) * 8;
            const float* gb = B + (size_t)(kt + bk) * N + n0 + bn;
            f32x4 g0 = *(const f32x4*)gb;
            f32x4 g1 = *(const f32x4*)(gb + 4);
#pragma unroll
            for (int p = 0; p < 4; ++p) { vb[r][p] = f2bf(g0[p]); vb[r][p + 4] = f2bf(g1[p]); }
        }
        __syncthreads();
#pragma unroll
        for (int r = 0; r < 2; ++r) {
            int c = t + r * 256;
            *(u16x8*)((char*)sA + (size_t)c * 16) = va[r];
            int bk = c >> 4, bn = (c & 15) * 8;
            u16* dst = sB + bk * SBS + bn;
#pragma unroll
            for (int p = 0; p < 4; ++p) {
                u16x2 w; w[0] = vb[r][2 * p]; w[1] = vb[r][2 * p + 1];
                *(u16x2*)(dst + 2 * p) = w;
            }
        }
        __syncthreads();

        bf16x8 af[4], bfr[4];
#pragma unroll
        for (int i = 0; i < 4; ++i)
            af[i] = *(const bf16x8*)((const char*)sA + (wm + i * 16 + lr) * 64 + quad * 16);
#pragma unroll
        for (int i = 0; i < 4; ++i) {
            u16 tmp[8];
#pragma unroll
            for (int j = 0; j < 8; ++j)
                tmp[j] = sB[(quad * 8 + j) * SBS + (wn + i * 16 + lr)];
            __builtin_memcpy(&bfr[i], tmp, 16);
        }
#pragma unroll
        for (int i = 0; i < 4; ++i)
#pragma unroll
            for (int j = 0; j < 4; ++j)
                acc[i][j] = __builtin_amdgcn_mfma_f32_16x16x32_bf16(af[i], bfr[j], acc[i][j], 0, 0, 0);
    }
#pragma unroll
    for (int i = 0; i < 4; ++i) {
        int mrow = m0 + wm + i * 16 + quad * 4;
#pragma unroll
        for (int j = 0; j < 4; ++j) {
            int ncol = n0 + wn + j * 16 + lr;
#pragma unroll
            for (int r = 0; r < 4; ++r)
                Cp[(size_t)(mrow + r) * N + ncol] = acc[i][j][r];
        }
    }
}

// ---------------- LN2 + residual, fp32 in-place on d_out ----------------
__global__ __launch_bounds__(256) void ln2_res(
    float* Y, const float* __restrict__ ftb,
    const float* __restrict__ g2, const float* __restrict__ b2,
    const float* __restrict__ x, int ROWS)
{
    const int lane = threadIdx.x & 63;
    const int wid = blockIdx.x * (blockDim.x >> 6) + (threadIdx.x >> 6);
    const int nw = gridDim.x * (blockDim.x >> 6);
    const int h0 = lane * 16;

    float ftbv[16], gv[16], bv[16];
#pragma unroll
    for (int i = 0; i < 16; ++i) {
        ftbv[i] = ftb[h0 + i];
        gv[i] = g2[h0 + i];
        bv[i] = b2[h0 + i];
    }
    for (int r = wid; r < ROWS; r += nw) {
        float* yrow = Y + (size_t)r * 1024 + h0;
        float y[16], s = 0.f, sq = 0.f;
#pragma unroll
        for (int q = 0; q < 4; ++q) {
            f32x4 v = *(const f32x4*)(yrow + 4 * q);
#pragma unroll
            for (int p = 0; p < 4; ++p) y[4 * q + p] = v[p] + ftbv[4 * q + p];
        }
#pragma unroll
        for (int i = 0; i < 16; ++i) { s += y[i]; sq += y[i] * y[i]; }
        s = wsum(s); sq = wsum(sq);
        float mu = s * (1.f / 1024.f);
        float var = fmaxf(sq * (1.f / 1024.f) - mu * mu, 0.f);
        float rinv = rsqrtf(var + 1e-5f);

        const float* xrow = x + (size_t)r * 1024 + h0;
#pragma unroll
        for (int q = 0; q < 4; ++q) {
            f32x4 xv = *(const f32x4*)(xrow + 4 * q);
            f32x4 o;
#pragma unroll
            for (int p = 0; p < 4; ++p)
                o[p] = (y[4 * q + p] - mu) * rinv * gv[4 * q + p] + bv[4 * q + p] + xv[p];
            *(f32x4*)(yrow + 4 * q) = o;
        }
    }
}

extern "C" void kernel_launch(void* const* d_in, const int* in_sizes, int n_in,
                              void* d_out, int out_size, void* d_ws, size_t ws_size,
                              hipStream_t stream) {
    const float* x     = (const float*)d_in[0];
    const float* masks = (const float*)d_in[1];
    const float* emb   = (const float*)d_in[2];
    const float* ltw   = (const float*)d_in[3];
    const float* ltb   = (const float*)d_in[4];
    const float* g1    = (const float*)d_in[5];
    const float* b1    = (const float*)d_in[6];
    const float* ftw   = (const float*)d_in[7];
    const float* ftb   = (const float*)d_in[8];
    const float* g2    = (const float*)d_in[9];
    const float* b2    = (const float*)d_in[10];
    float* out = (float*)d_out;                   // [B,L,H] fp32 (128 MB)

    const int H = 1024, L = 4096;
    const int M = in_sizes[0] / H;                // B*L = 32768
    const size_t MB = 1024 * 1024;

    // memory plan:
    //  d_out lower 64 MB : plane0 (bf16 y1 / fused) — dead before fp32 C-write of GEMM2
    //  d_out upper 64 MB : x_bf16 (A for GEMM1)     — dead before GEMM2's C-write
    //  ws[0:64MB]        : aggP bf16
    //  ws[64:66MB]       : Bt1; ws[66:68MB] : Bt2 (roomy only)
    //  tight-ws          : Bt1 aliases ws[0:2MB] (dead before agg written);
    //                      GEMM2 falls back to reg-staged fp32-B kernel (no Bt2).
    u16* plane0 = (u16*)d_out;
    u16* xbf    = (u16*)((char*)d_out + 64 * MB);
    u16* aggP   = (u16*)d_ws;
    const bool roomy = ws_size >= 68 * MB;
    u16* Bt1 = roomy ? (u16*)((char*)d_ws + 64 * MB) : (u16*)d_ws;
    u16* Bt2 = roomy ? (u16*)((char*)d_ws + 66 * MB) : nullptr;

    f32_to_bf16<<<2048, 256, 0, stream>>>(x, xbf, M * H / 8);
    w_transpose<<<dim3(16, 16), 256, 0, stream>>>(ltw, Bt1, H, H);
    if (roomy) w_transpose<<<dim3(16, 16), 256, 0, stream>>>(ftw, Bt2, H, H);

    gemm_bt<0><<<dim3(H / 128, M / 128), 256, 0, stream>>>(xbf, Bt1, plane0, M, H, H);  // y1 bf16
    ln1_fusion<<<1024, 256, 0, stream>>>(plane0, ltb, g1, b1, masks, emb, plane0, M);   // fused in-place
    multiscale_slide<<<(M / MS_SEG) * 2, 256, 0, stream>>>(plane0, aggP, L);            // agg -> ws
    if (roomy)
        gemm_bt<1><<<dim3(H / 128, M / 128), 256, 0, stream>>>(aggP, Bt2, out, M, H, H);
    else
        gemm_k_bf_f32<<<dim3(H / BN, M / BM), 256, 0, stream>>>(aggP, ftw, out, M, H, H);
    ln2_res<<<1024, 256, 0, stream>>>(out, ftb, g2, b2, x, M);
}